// Round 7
// baseline (182.010 us; speedup 1.0000x reference)
//
#include <hip/hip_runtime.h>
#include <hip/hip_cooperative_groups.h>

#define BB 32
#define LL 512
#define TT 48
#define START_ID 46
#define END_ID 47

constexpr int   BLT  = BB * LL * TT;        // 786432 feature rows-elements
constexpr unsigned NSC = 37748736u;         // B*L*T*T scores elements
constexpr unsigned NGRP = 9437183u;         // float4 groups at scores idx 3+4k

// ---- tree parameters ----
constexpr int SEGS   = 31;                  // segments per batch (16 steps each, t=1..496)
constexpr int SEGLEN = 16;
constexpr int GW     = 1152;                // dwords per 48x48 f16 G matrix
constexpr int NSEG   = BB * SEGS;           // 992
constexpr int SOFF   = NSEG * GW;           // dword offset of Sacc[NSEG]
constexpr int ZOFF   = SOFF + NSEG;         // dword offset of logZ[32]
constexpr size_t WS_NEED = (size_t)(ZOFF + 32) * 4;

constexpr int NB_WRITE = 2048;              // pure writer blocks in launch 2

typedef __fp16 f16x2 __attribute__((ext_vector_type(2)));
typedef __fp16 f16x8 __attribute__((ext_vector_type(8)));
typedef float  f32x4 __attribute__((ext_vector_type(4)));
typedef unsigned u32x4 __attribute__((ext_vector_type(4)));

__device__ __forceinline__ float fexp2(float x) { return __builtin_amdgcn_exp2f(x); }
__device__ __forceinline__ float flog2(float x) { return __builtin_amdgcn_logf(x); }
__device__ __forceinline__ float rfirst(float x) {
  return __uint_as_float(__builtin_amdgcn_readfirstlane(__float_as_uint(x)));
}
__device__ __forceinline__ float fdot2(f16x2 a, f16x2 b, float c) {
  return __builtin_amdgcn_fdot2(a, b, c, false);
}
__device__ __forceinline__ f16x2 bc(unsigned u) { return __builtin_bit_cast(f16x2, u); }
__device__ __forceinline__ unsigned pk2(float a, float b) {
  return __builtin_bit_cast(unsigned, __builtin_amdgcn_cvt_pkrtz(a, b));
}
__device__ __forceinline__ float dpp_xor1(float x) {
  return __int_as_float(__builtin_amdgcn_update_dpp(
      __float_as_int(x), __float_as_int(x), 0xB1, 0xF, 0xF, true));
}
__device__ __forceinline__ f16x8 b8(unsigned d0, unsigned d1) {
  u32x4 u; u.x = d0; u.y = d1; u.z = 0u; u.w = 0u;
  return __builtin_bit_cast(f16x8, u);
}
__device__ __forceinline__ f32x4 MF(f16x8 a, f16x8 b, f32x4 c) {
  return __builtin_amdgcn_mfma_f32_16x16x32_f16(a, b, c, 0, 0, 0);
}

#define GLD16(gp, lp)                                                        \
  __builtin_amdgcn_global_load_lds(                                          \
      (const __attribute__((address_space(1))) unsigned int*)(gp),           \
      (__attribute__((address_space(3))) unsigned int*)(lp), 16, 0, 0)

// ================= tree body: segment product G = A_{16s+16}..A_{16s+1} =========
// Verbatim round-3 verified math. No fences.
__device__ __attribute__((noinline)) void crf_tree_body(
    const float* __restrict__ feat, const float* __restrict__ trans,
    float* __restrict__ ws, float* lds, int wg, int lane)
{
  constexpr float LOG2E = 1.4426950408889634f;
  unsigned* gws = (unsigned*)ws;
  const int b  = wg / SEGS, s = wg - b * SEGS;
  const int col = lane & 15, grp = lane >> 4, rb = grp * 4;

  const char* gbase = (const char*)feat + (size_t)b * 98304 + (size_t)(SEGLEN * s + 1) * 192;
#pragma unroll
  for (int w = 0; w < 3; ++w)
    GLD16(gbase + w * 1024 + lane * 16, (char*)lds + w * 1024);

  float4 T_[3][3];
#pragma unroll
  for (int I = 0; I < 3; ++I)
#pragma unroll
    for (int K = 0; K < 3; ++K) {
      const float4 t4 = *(const float4*)(trans + (I * 16 + col) * 48 + K * 16 + rb);
      T_[I][K].x = fexp2(t4.x * LOG2E);
      T_[I][K].y = fexp2(t4.y * LOG2E);
      T_[I][K].z = fexp2(t4.z * LOG2E);
      T_[I][K].w = fexp2(t4.w * LOG2E);
    }

  unsigned Bd[3][3][2];
#pragma unroll
  for (int K = 0; K < 3; ++K)
#pragma unroll
    for (int J = 0; J < 3; ++J) {
      const float b0 = (K == J && rb + 0 == col) ? 1.f : 0.f;
      const float b1 = (K == J && rb + 1 == col) ? 1.f : 0.f;
      const float b2 = (K == J && rb + 2 == col) ? 1.f : 0.f;
      const float b3 = (K == J && rb + 3 == col) ? 1.f : 0.f;
      Bd[K][J][0] = pk2(b0, b1);
      Bd[K][J][1] = pk2(b2, b3);
    }

  asm volatile("s_waitcnt vmcnt(0)" ::: "memory");
  __builtin_amdgcn_sched_barrier(0);

  float km = 0.f, Sacc = 0.f;
  f32x4 C[3][3];
  const f32x4 zz = {0.f, 0.f, 0.f, 0.f};

  for (int p = 0; p < SEGLEN; ++p) {
    Sacc += km;
    float ef[3];
    ef[0] = fexp2(fmaf(lds[p * 48 +  0 + col], LOG2E, -km));
    ef[1] = fexp2(fmaf(lds[p * 48 + 16 + col], LOG2E, -km));
    ef[2] = fexp2(fmaf(lds[p * 48 + 32 + col], LOG2E, -km));
    f16x8 A_[3][3];
#pragma unroll
    for (int I = 0; I < 3; ++I)
#pragma unroll
      for (int K = 0; K < 3; ++K) {
        u32x4 u;
        u.x = pk2(T_[I][K].x * ef[I], T_[I][K].y * ef[I]);
        u.y = pk2(T_[I][K].z * ef[I], T_[I][K].w * ef[I]);
        u.z = 0u; u.w = 0u;
        A_[I][K] = __builtin_bit_cast(f16x8, u);
      }
#pragma unroll
    for (int I = 0; I < 3; ++I)
#pragma unroll
      for (int J = 0; J < 3; ++J) {
        f32x4 c = MF(A_[I][0], b8(Bd[0][J][0], Bd[0][J][1]), zz);
        c = MF(A_[I][1], b8(Bd[1][J][0], Bd[1][J][1]), c);
        c = MF(A_[I][2], b8(Bd[2][J][0], Bd[2][J][1]), c);
        C[I][J] = c;
      }
    const unsigned u00 = __builtin_amdgcn_readfirstlane(__float_as_uint(C[0][0][0]));
    km = (float)((int)((u00 >> 23) & 255u) - 127);
#pragma unroll
    for (int K = 0; K < 3; ++K)
#pragma unroll
      for (int J = 0; J < 3; ++J) {
        Bd[K][J][0] = pk2(C[K][J][0], C[K][J][1]);
        Bd[K][J][1] = pk2(C[K][J][2], C[K][J][3]);
      }
  }

  const unsigned gb = (unsigned)wg * GW;
#pragma unroll
  for (int I = 0; I < 3; ++I)
#pragma unroll
    for (int J = 0; J < 3; ++J)
#pragma unroll
      for (int r = 0; r < 4; ++r) {
        const float cn = dpp_xor1(C[I][J][r]);
        const unsigned pk = pk2(C[I][J][r], cn);
        if (!(col & 1))
          gws[gb + (unsigned)((I * 16 + rb + r) * 24 + ((J * 16 + col) >> 1))] = pk;
      }
  if (lane == 0) ws[SOFF + wg] = Sacc;
}

// standalone tree launch (R3 fallback structure)
__global__ __launch_bounds__(64) void crf_tree_kernel(
    const float* __restrict__ feat, const float* __restrict__ trans,
    float* __restrict__ ws)
{
  __shared__ __align__(16) float fls[SEGLEN * 48];
  crf_tree_body(feat, trans, ws, fls, blockIdx.x, threadIdx.x);
}

// ================= phaseB: per-batch segment matvecs + tail (fence-free) =========
__device__ __attribute__((noinline)) void crf_phaseB(
    const float* __restrict__ feat, const float* __restrict__ trans,
    const int* __restrict__ seqLens, float* __restrict__ ws, int b, int lane)
{
  constexpr float LOG2E = 1.4426950408889634f;
  constexpr float LN2   = 0.6931471805599453f;
  const unsigned* gws = (const unsigned*)ws;
  const int ii = lane < 47 ? lane : 47;
  const int Lb = seqLens[b];
  const int steps = Lb - 1;                    // 0..511
  const int nfull = steps >> 4;                // full 16-step segments (<= 31)

  f16x2 E00,E01,E02,E03,E04,E05,E06,E07,E08,E09,E10,E11,
        E12,E13,E14,E15,E16,E17,E18,E19,E20,E21,E22,E23;
#define LDE(V, J) { const float e0_ = fexp2(trans[ii*48 + 2*(J)]     * LOG2E); \
                    const float e1_ = fexp2(trans[ii*48 + 2*(J) + 1] * LOG2E); \
                    V = __builtin_amdgcn_cvt_pkrtz(e0_, e1_); }
  LDE(E00,0)  LDE(E01,1)  LDE(E02,2)  LDE(E03,3)  LDE(E04,4)  LDE(E05,5)
  LDE(E06,6)  LDE(E07,7)  LDE(E08,8)  LDE(E09,9)  LDE(E10,10) LDE(E11,11)
  LDE(E12,12) LDE(E13,13) LDE(E14,14) LDE(E15,15) LDE(E16,16) LDE(E17,17)
  LDE(E18,18) LDE(E19,19) LDE(E20,20) LDE(E21,21) LDE(E22,22) LDE(E23,23)
#undef LDE
  const float tS = trans[ii * 48 + START_ID];
  const float tE = trans[END_ID * 48 + ii];
  const float* fb = feat + (size_t)b * (LL * TT);

  const float a0 = (tS + fb[ii]) * LOG2E;
  const float anch = rfirst(a0);
  float v = fexp2(a0 - anch);
  float sigma = anch;

#define RL24                                                               \
        unsigned s00,s01,s02,s03,s04,s05,s06,s07,s08,s09,s10,s11,          \
                 s12,s13,s14,s15,s16,s17,s18,s19,s20,s21,s22,s23;          \
        s00=__builtin_amdgcn_readlane(pku,0);  s01=__builtin_amdgcn_readlane(pku,2);  \
        s02=__builtin_amdgcn_readlane(pku,4);  s03=__builtin_amdgcn_readlane(pku,6);  \
        s04=__builtin_amdgcn_readlane(pku,8);  s05=__builtin_amdgcn_readlane(pku,10); \
        s06=__builtin_amdgcn_readlane(pku,12); s07=__builtin_amdgcn_readlane(pku,14); \
        s08=__builtin_amdgcn_readlane(pku,16); s09=__builtin_amdgcn_readlane(pku,18); \
        s10=__builtin_amdgcn_readlane(pku,20); s11=__builtin_amdgcn_readlane(pku,22); \
        s12=__builtin_amdgcn_readlane(pku,24); s13=__builtin_amdgcn_readlane(pku,26); \
        s14=__builtin_amdgcn_readlane(pku,28); s15=__builtin_amdgcn_readlane(pku,30); \
        s16=__builtin_amdgcn_readlane(pku,32); s17=__builtin_amdgcn_readlane(pku,34); \
        s18=__builtin_amdgcn_readlane(pku,36); s19=__builtin_amdgcn_readlane(pku,38); \
        s20=__builtin_amdgcn_readlane(pku,40); s21=__builtin_amdgcn_readlane(pku,42); \
        s22=__builtin_amdgcn_readlane(pku,44); s23=__builtin_amdgcn_readlane(pku,46);

  // ---- segment matvecs with 1-ahead register prefetch of G ----
  const unsigned* grow = gws + (size_t)(b * SEGS) * GW + ii * 24;
  u32x4 h0,h1,h2,h3,h4,h5, n0,n1,n2,n3,n4,n5;
  if (nfull > 0) {
    const u32x4* gp = (const u32x4*)grow;
    h0 = gp[0]; h1 = gp[1]; h2 = gp[2]; h3 = gp[3]; h4 = gp[4]; h5 = gp[5];
  }
  for (int s = 0; s < nfull; ++s) {
    if (s + 1 < nfull) {
      const u32x4* gp = (const u32x4*)(grow + (size_t)(s + 1) * GW);
      n0 = gp[0]; n1 = gp[1]; n2 = gp[2]; n3 = gp[3]; n4 = gp[4]; n5 = gp[5];
    }
    const float pn = dpp_xor1(v);
    const unsigned pku = pk2(v, pn);
    RL24
    float d0, d1, d2, d3;
    d0 = fdot2(bc(h0.x), bc(s00), 0.0f);
    d1 = fdot2(bc(h0.y), bc(s01), 0.0f);
    d2 = fdot2(bc(h0.z), bc(s02), 0.0f);
    d3 = fdot2(bc(h0.w), bc(s03), 0.0f);
    d0 = fdot2(bc(h1.x), bc(s04), d0);
    d1 = fdot2(bc(h1.y), bc(s05), d1);
    d2 = fdot2(bc(h1.z), bc(s06), d2);
    d3 = fdot2(bc(h1.w), bc(s07), d3);
    d0 = fdot2(bc(h2.x), bc(s08), d0);
    d1 = fdot2(bc(h2.y), bc(s09), d1);
    d2 = fdot2(bc(h2.z), bc(s10), d2);
    d3 = fdot2(bc(h2.w), bc(s11), d3);
    d0 = fdot2(bc(h3.x), bc(s12), d0);
    d1 = fdot2(bc(h3.y), bc(s13), d1);
    d2 = fdot2(bc(h3.z), bc(s14), d2);
    d3 = fdot2(bc(h3.w), bc(s15), d3);
    d0 = fdot2(bc(h4.x), bc(s16), d0);
    d1 = fdot2(bc(h4.y), bc(s17), d1);
    d2 = fdot2(bc(h4.z), bc(s18), d2);
    d3 = fdot2(bc(h4.w), bc(s19), d3);
    d0 = fdot2(bc(h5.x), bc(s20), d0);
    d1 = fdot2(bc(h5.y), bc(s21), d1);
    d2 = fdot2(bc(h5.z), bc(s22), d2);
    d3 = fdot2(bc(h5.w), bc(s23), d3);
    const float dot = (d0 + d1) + (d2 + d3);
    const unsigned ub = __builtin_amdgcn_readfirstlane(__float_as_uint(dot));
    const int e = (int)((ub >> 23) & 255u) - 127;
    v = dot * __uint_as_float((unsigned)(127 - e) << 23);
    sigma += (float)e + ws[SOFF + b * SEGS + s];
    h0 = n0; h1 = n1; h2 = n2; h3 = n3; h4 = n4; h5 = n5;
  }

  // ---- tail: t = 16*nfull+1 .. steps (<= 15 scalar steps) ----
  int t = nfull * 16 + 1;
  if (t <= steps) {
    float f_cur = fb[(size_t)t * 48 + ii];
    for (; t <= steps; ++t) {
      const int tn = (t + 1 <= steps) ? t + 1 : t;
      const float f_nxt = fb[(size_t)tn * 48 + ii];
      const float pn = dpp_xor1(v);
      const unsigned pku = pk2(v, pn);
      RL24
      float d0, d1, d2, d3;
      d0 = fdot2(E00, bc(s00), 0.0f);
      d1 = fdot2(E01, bc(s01), 0.0f);
      d2 = fdot2(E02, bc(s02), 0.0f);
      d3 = fdot2(E03, bc(s03), 0.0f);
      d0 = fdot2(E04, bc(s04), d0);
      d1 = fdot2(E05, bc(s05), d1);
      d2 = fdot2(E06, bc(s06), d2);
      d3 = fdot2(E07, bc(s07), d3);
      d0 = fdot2(E08, bc(s08), d0);
      d1 = fdot2(E09, bc(s09), d1);
      d2 = fdot2(E10, bc(s10), d2);
      d3 = fdot2(E11, bc(s11), d3);
      d0 = fdot2(E12, bc(s12), d0);
      d1 = fdot2(E13, bc(s13), d1);
      d2 = fdot2(E14, bc(s14), d2);
      d3 = fdot2(E15, bc(s15), d3);
      d0 = fdot2(E16, bc(s16), d0);
      d1 = fdot2(E17, bc(s17), d1);
      d2 = fdot2(E18, bc(s18), d2);
      d3 = fdot2(E19, bc(s19), d3);
      d0 = fdot2(E20, bc(s20), d0);
      d1 = fdot2(E21, bc(s21), d1);
      d2 = fdot2(E22, bc(s22), d2);
      d3 = fdot2(E23, bc(s23), d3);
      const float dot = (d0 + d1) + (d2 + d3);
      const float w = dot * fexp2(f_cur * LOG2E);
      const unsigned ub = __builtin_amdgcn_readfirstlane(__float_as_uint(w));
      const int e = (int)((ub >> 23) & 255u) - 127;
      v = w * __uint_as_float((unsigned)(127 - e) << 23);
      sigma += (float)e;
      f_cur = f_nxt;
    }
  }
#undef RL24

  float contrib = (lane < 48) ? v * fexp2(tE * LOG2E) : 0.0f;
#pragma unroll
  for (int off = 32; off; off >>= 1) contrib += __shfl_xor(contrib, off, 64);
  if (lane == 0) ws[ZOFF + b] = (flog2(contrib) + sigma) * LN2;
}

// ================= coop launch 1: tree -> grid.sync -> phaseB =================
__global__ __launch_bounds__(64) void crf_coop_kernel(
    const float* __restrict__ feat, const float* __restrict__ trans,
    const int* __restrict__ seqLens, float* __restrict__ ws)
{
  __shared__ __align__(16) float fls[SEGLEN * 48];
  crf_tree_body(feat, trans, ws, fls, blockIdx.x, threadIdx.x);
  cooperative_groups::this_grid().sync();     // one barrier, HBM idle here
  if (blockIdx.x < BB)
    crf_phaseB(feat, trans, seqLens, ws, blockIdx.x, threadIdx.x);
}

// ================= writer body (range-parametrized) =================
__device__ __forceinline__ void scores_writer_rng(
    const float* __restrict__ feat, float* __restrict__ out,
    float* lds, unsigned k, unsigned kstride, unsigned kend)
{
  for (; k < kend; k += kstride) {
    const unsigned idx = 3u + 4u * k;
    const unsigned r0 = idx / 48u;
    const unsigned j0 = idx - r0 * 48u;
    const unsigned i0 = r0 % 48u;
    const unsigned rn = (r0 + 1u < (unsigned)BLT) ? r0 + 1u : (unsigned)(BLT - 1);
    const float fa = feat[r0];
    const float fn = feat[rn];
    const unsigned i1 = (i0 + 1u < 48u) ? i0 + 1u : 0u;
    float v[4];
#pragma unroll
    for (int e = 0; e < 4; ++e) {
      const unsigned j = j0 + (unsigned)e;
      const bool wr = j >= 48u;
      const unsigned jj = wr ? j - 48u : j;
      v[e] = (wr ? fn : fa) + lds[(wr ? i1 : i0) * 48u + jj];
    }
    float4 o; o.x = v[0]; o.y = v[1]; o.z = v[2]; o.w = v[3];
    *(float4*)(out + 4u + 4u * (size_t)k) = o;
  }
}

// ================= launch 2: pure writers + 1 finalizer block =================
__global__ __launch_bounds__(256) void crf_writer_kernel(
    const float* __restrict__ feat, const float* __restrict__ trans,
    const float* __restrict__ ws, float* __restrict__ out)
{
  __shared__ __align__(16) float lds[2304];
  const int blk = blockIdx.x;
  const int tid = threadIdx.x;

  if (blk == NB_WRITE) {                      // finalizer: logZ sum + edges
    if (tid >= 64) return;
    float v = (tid < 32) ? ws[ZOFF + tid] : 0.0f;
#pragma unroll
    for (int off = 32; off; off >>= 1) v += __shfl_xor(v, off, 64);
    if (tid == 0) out[0] = v;
    else if (tid <= 3) out[tid] = feat[0] + trans[tid - 1];
    else if (tid == 4) out[NSC] = feat[BLT - 1] + trans[2303];
    return;
  }

  for (int s = tid; s < 2304; s += 256) lds[s] = trans[s];
  __syncthreads();
  scores_writer_rng(feat, out, lds,
                    (unsigned)blk * 256u + tid,
                    (unsigned)NB_WRITE * 256u, NGRP);
}

// ================= R3 fallback: fusedB (phaseB + writers) + finalize ===========
__global__ __launch_bounds__(256) void crf_fusedB_kernel(
    const float* __restrict__ feat, const float* __restrict__ trans,
    const int* __restrict__ seqLens, float* __restrict__ out,
    float* __restrict__ ws)
{
  __shared__ __align__(16) float lds[2304];
  const int blk = blockIdx.x;
  if (blk < BB) {
    if (threadIdx.x >= 64) return;
    crf_phaseB(feat, trans, seqLens, ws, blk, threadIdx.x);
    return;
  }
  for (int s = threadIdx.x; s < 2304; s += 256) lds[s] = trans[s];
  __syncthreads();
  scores_writer_rng(feat, out, lds,
                    (unsigned)(blk - BB) * 256u + threadIdx.x,
                    (gridDim.x - BB) * 256u, NGRP);
}

__global__ void crf_finalize_kernel(const float* __restrict__ feat,
                                    const float* __restrict__ trans,
                                    const float* __restrict__ zws,
                                    float* __restrict__ out)
{
  const int t = threadIdx.x;
  float v = (t < 32) ? zws[t] : 0.0f;
#pragma unroll
  for (int off = 32; off; off >>= 1) v += __shfl_xor(v, off, 64);
  if (t == 0) out[0] = v;
  else if (t <= 3) out[t] = feat[0] + trans[t - 1];
  else if (t == 4) out[NSC] = feat[BLT - 1] + trans[2303];
}

// ================= ws-too-small fallback: verified 88us scalar recursion ========
__device__ __attribute__((noinline)) void crf_recursion_body(
    const float* __restrict__ feat, const float* __restrict__ trans,
    const int* __restrict__ seqLens, float* __restrict__ ws,
    float* lds, int blk, int lane)
{
  constexpr float LOG2E = 1.4426950408889634f;
  const int ii = lane < 47 ? lane : 47;
  const char* gbase = (const char*)(feat + (size_t)blk * (LL * TT));
  const int Lb = seqLens[blk];

#pragma unroll
  for (int w = 0; w < 6; ++w)
    GLD16(gbase + w * 1024 + lane * 16, (char*)&lds[0] + w * 1024);

  f16x2 E00,E01,E02,E03,E04,E05,E06,E07,E08,E09,E10,E11,
        E12,E13,E14,E15,E16,E17,E18,E19,E20,E21,E22,E23;
#define LDE(V, J) { const float e0_ = fexp2(trans[ii*48 + 2*(J)]     * LOG2E); \
                    const float e1_ = fexp2(trans[ii*48 + 2*(J) + 1] * LOG2E); \
                    V = __builtin_amdgcn_cvt_pkrtz(e0_, e1_); }
  LDE(E00,0)  LDE(E01,1)  LDE(E02,2)  LDE(E03,3)  LDE(E04,4)  LDE(E05,5)
  LDE(E06,6)  LDE(E07,7)  LDE(E08,8)  LDE(E09,9)  LDE(E10,10) LDE(E11,11)
  LDE(E12,12) LDE(E13,13) LDE(E14,14) LDE(E15,15) LDE(E16,16) LDE(E17,17)
  LDE(E18,18) LDE(E19,19) LDE(E20,20) LDE(E21,21) LDE(E22,22) LDE(E23,23)
#undef LDE
  const float tS = trans[ii * 48 + START_ID];
  const float tE = trans[END_ID * 48 + ii];

  asm volatile("s_waitcnt vmcnt(0)" ::: "memory");
  __builtin_amdgcn_sched_barrier(0);

  const float f00 = lds[ii];
  float a2 = (tS + f00) * LOG2E;
  float M2 = rfirst(a2) + 5.0f;

  const int nch = (Lb + 31) >> 5;
  for (int c = 0; c < nch; ++c) {
    const bool pre = (c + 1 < nch);
    if (pre) {
      const char* g = gbase + (size_t)(c + 1) * 6144;
      char* l = (char*)&lds[((c + 1) & 1) * 1536];
#pragma unroll
      for (int w = 0; w < 6; ++w) GLD16(g + w * 1024 + lane * 16, l + w * 1024);
    }
    const int tend = ((c + 1) * 32 < Lb) ? (c + 1) * 32 : Lb;
    const int t0 = (c == 0 ? 1 : c * 32);
    const int base = (c & 1) * 1536 + ii;
    if (t0 < tend) {
      float f_cur = lds[base + (t0 - c * 32) * 48];
      for (int t = t0; t < tend; ++t) {
        const int lnxt = ((t + 1 < tend) ? t + 1 : t) - c * 32;
        const float f_nxt = lds[base + lnxt * 48];
        const float p  = fexp2(a2 - M2);
        const float pn = dpp_xor1(p);
        const unsigned pku = pk2(p, pn);
        unsigned s00,s01,s02,s03,s04,s05,s06,s07,s08,s09,s10,s11,
                 s12,s13,s14,s15,s16,s17,s18,s19,s20,s21,s22,s23;
#define RL(K) __builtin_amdgcn_readlane(pku, (K))
        s00=RL(0);  s01=RL(2);  s02=RL(4);  s03=RL(6);
        s04=RL(8);  s05=RL(10); s06=RL(12); s07=RL(14);
        s08=RL(16); s09=RL(18); s10=RL(20); s11=RL(22);
        s12=RL(24); s13=RL(26); s14=RL(28); s15=RL(30);
        s16=RL(32); s17=RL(34); s18=RL(36); s19=RL(38);
        s20=RL(40); s21=RL(42); s22=RL(44); s23=RL(46);
#undef RL
        float d0, d1, d2, d3;
        d0 = fdot2(E00, bc(s00), 0.0f);
        d1 = fdot2(E01, bc(s01), 0.0f);
        d2 = fdot2(E02, bc(s02), 0.0f);
        d3 = fdot2(E03, bc(s03), 0.0f);
        d0 = fdot2(E04, bc(s04), d0);
        d1 = fdot2(E05, bc(s05), d1);
        d2 = fdot2(E06, bc(s06), d2);
        d3 = fdot2(E07, bc(s07), d3);
        d0 = fdot2(E08, bc(s08), d0);
        d1 = fdot2(E09, bc(s09), d1);
        d2 = fdot2(E10, bc(s10), d2);
        d3 = fdot2(E11, bc(s11), d3);
        d0 = fdot2(E12, bc(s12), d0);
        d1 = fdot2(E13, bc(s13), d1);
        d2 = fdot2(E14, bc(s14), d2);
        d3 = fdot2(E15, bc(s15), d3);
        d0 = fdot2(E16, bc(s16), d0);
        d1 = fdot2(E17, bc(s17), d1);
        d2 = fdot2(E18, bc(s18), d2);
        d3 = fdot2(E19, bc(s19), d3);
        d0 = fdot2(E20, bc(s20), d0);
        d1 = fdot2(E21, bc(s21), d1);
        d2 = fdot2(E22, bc(s22), d2);
        d3 = fdot2(E23, bc(s23), d3);
        const float dot = (d0 + d1) + (d2 + d3);
        a2 = fmaf(f_cur, LOG2E, M2 + flog2(dot));
        M2 = rfirst(a2) + 5.0f;
        f_cur = f_nxt;
      }
    }
    asm volatile("s_waitcnt vmcnt(0)" ::: "memory");
    __builtin_amdgcn_sched_barrier(0);
  }

  float last2 = (lane < 48) ? (a2 + tE * LOG2E) : -3.0e38f;
  float m2 = last2;
#pragma unroll
  for (int off = 32; off; off >>= 1) m2 = fmaxf(m2, __shfl_xor(m2, off, 64));
  float e = (lane < 48) ? fexp2(last2 - m2) : 0.0f;
#pragma unroll
  for (int off = 32; off; off >>= 1) e += __shfl_xor(e, off, 64);
  if (lane == 0) ws[blk] = (m2 + flog2(e)) * 0.6931471805599453f;
}

__global__ __launch_bounds__(256) void crf_fused2_kernel(
    const float* __restrict__ feat, const float* __restrict__ trans,
    const int* __restrict__ seqLens, float* __restrict__ out,
    float* __restrict__ ws)
{
  __shared__ __align__(16) float lds[3072];
  const int blk = blockIdx.x;
  if (blk < BB) {
    if (threadIdx.x >= 64) return;
    crf_recursion_body(feat, trans, seqLens, ws, lds, blk, threadIdx.x);
    return;
  }
  for (int s = threadIdx.x; s < 2304; s += 256) lds[s] = trans[s];
  __syncthreads();
  scores_writer_rng(feat, out, lds,
                    (unsigned)(blk - BB) * 256u + threadIdx.x,
                    (gridDim.x - BB) * 256u, NGRP);
}

// ================= host =================
extern "C" void kernel_launch(void* const* d_in, const int* in_sizes, int n_in,
                              void* d_out, int out_size, void* d_ws, size_t ws_size,
                              hipStream_t stream) {
  const float* feat    = (const float*)d_in[0];
  const float* trans   = (const float*)d_in[1];
  const int*   seqLens = (const int*)d_in[2];
  float* out = (float*)d_out;
  float* ws  = (float*)d_ws;

  static int coop_ok = -1;
  if (coop_ok < 0) {
    int dev = 0;
    (void)hipGetDevice(&dev);
    int v = 0;
    if (hipDeviceGetAttribute(&v, hipDeviceAttributeCooperativeLaunch, dev) != hipSuccess)
      v = 0;
    coop_ok = v;
  }

  if (ws_size >= WS_NEED && coop_ok) {
    void* a1[] = {(void*)&feat, (void*)&trans, (void*)&seqLens, (void*)&ws};
    hipLaunchCooperativeKernel((const void*)crf_coop_kernel, dim3(NSEG), dim3(64),
                               a1, 0, stream);
    hipLaunchKernelGGL(crf_writer_kernel, dim3(NB_WRITE + 1), dim3(256), 0, stream,
                       feat, trans, ws, out);
  } else if (ws_size >= WS_NEED) {
    // R3-verified 3-launch pipeline
    hipLaunchKernelGGL(crf_tree_kernel, dim3(NSEG), dim3(64), 0, stream,
                       feat, trans, ws);
    hipLaunchKernelGGL(crf_fusedB_kernel, dim3(2048), dim3(256), 0, stream,
                       feat, trans, seqLens, out, ws);
    hipLaunchKernelGGL(crf_finalize_kernel, dim3(1), dim3(64), 0, stream,
                       feat, trans, ws + ZOFF, out);
  } else {
    hipLaunchKernelGGL(crf_fused2_kernel, dim3(2048), dim3(256), 0, stream,
                       feat, trans, seqLens, out, ws);
    hipLaunchKernelGGL(crf_finalize_kernel, dim3(1), dim3(64), 0, stream,
                       feat, trans, ws, out);
  }
}

// Round 9
// 57.495 us; speedup vs baseline: 3.1657x; 3.1657x over previous
//
#include <hip/hip_runtime.h>

#define BB 32
#define LL 512
#define TT 48
#define START_ID 46
#define END_ID 47

constexpr int   BLT  = BB * LL * TT;        // 786432 feature rows-elements
constexpr unsigned NSC = 37748736u;         // B*L*T*T scores elements
constexpr unsigned NGRP = 9437183u;         // float4 groups at scores idx 3+4k

// ---- tree parameters ----
constexpr int SEGS   = 31;                  // segments per batch (16 steps each, t=1..496)
constexpr int SEGLEN = 16;
constexpr int GW     = 1152;                // dwords per 48x48 f16 G matrix
constexpr int NSEG   = BB * SEGS;           // 992
constexpr int SOFF   = NSEG * GW;           // dword offset of Sacc[NSEG]
constexpr int ZOFF   = SOFF + NSEG;         // dword offset of logZ[32]
constexpr size_t WS_NEED = (size_t)(ZOFF + 32) * 4;

typedef __fp16 f16x2 __attribute__((ext_vector_type(2)));
typedef __fp16 f16x4 __attribute__((ext_vector_type(4)));
typedef float  f32x4 __attribute__((ext_vector_type(4)));
typedef unsigned u32x2 __attribute__((ext_vector_type(2)));
typedef unsigned u32x4 __attribute__((ext_vector_type(4)));

__device__ __forceinline__ float fexp2(float x) { return __builtin_amdgcn_exp2f(x); }
__device__ __forceinline__ float flog2(float x) { return __builtin_amdgcn_logf(x); }
__device__ __forceinline__ float rfirst(float x) {
  return __uint_as_float(__builtin_amdgcn_readfirstlane(__float_as_uint(x)));
}
__device__ __forceinline__ float fdot2(f16x2 a, f16x2 b, float c) {
  return __builtin_amdgcn_fdot2(a, b, c, false);
}
__device__ __forceinline__ f16x2 bc(unsigned u) { return __builtin_bit_cast(f16x2, u); }
__device__ __forceinline__ unsigned pk2(float a, float b) {
  return __builtin_bit_cast(unsigned, __builtin_amdgcn_cvt_pkrtz(a, b));
}
__device__ __forceinline__ float dpp_xor1(float x) {
  return __int_as_float(__builtin_amdgcn_update_dpp(
      __float_as_int(x), __float_as_int(x), 0xB1, 0xF, 0xF, true));
}
// K=16 native fragments (2 VGPRs): natural mapping k=(l>>4)*4+e, no pad
__device__ __forceinline__ f16x4 b4(unsigned d0, unsigned d1) {
  u32x2 u; u.x = d0; u.y = d1;
  return __builtin_bit_cast(f16x4, u);
}
__device__ __forceinline__ f32x4 MF16(f16x4 a, f16x4 b, f32x4 c) {
  // NOTE gfx950 spelling: legacy K=16 shape has NO underscore before f16
  return __builtin_amdgcn_mfma_f32_16x16x16f16(a, b, c, 0, 0, 0);
}

#define GLD16(gp, lp)                                                        \
  __builtin_amdgcn_global_load_lds(                                          \
      (const __attribute__((address_space(1))) unsigned int*)(gp),           \
      (__attribute__((address_space(3))) unsigned int*)(lp), 16, 0, 0)

// ================= tree body: segment product G = A_{16s+16}..A_{16s+1} =========
// R3-verified math, MFMA shape switched 16x16x32(zero-pad) -> native 16x16x16.
// With K=16 the A-pack, identity-B and C->B repack all use the natural k map:
// A[row=l&15][k=rb+e], B[k=rb+e][col=l&15], C[row=rb+r][col=l&15]  (rb=(l>>4)*4)
__device__ __attribute__((noinline)) void crf_tree_body(
    const float* __restrict__ feat, const float* __restrict__ trans,
    float* __restrict__ ws, float* lds, int wg, int lane)
{
  constexpr float LOG2E = 1.4426950408889634f;
  unsigned* gws = (unsigned*)ws;
  const int b  = wg / SEGS, s = wg - b * SEGS;
  const int col = lane & 15, grp = lane >> 4, rb = grp * 4;

  const char* gbase = (const char*)feat + (size_t)b * 98304 + (size_t)(SEGLEN * s + 1) * 192;
#pragma unroll
  for (int w = 0; w < 3; ++w)
    GLD16(gbase + w * 1024 + lane * 16, (char*)lds + w * 1024);

  float4 T_[3][3];
#pragma unroll
  for (int I = 0; I < 3; ++I)
#pragma unroll
    for (int K = 0; K < 3; ++K) {
      const float4 t4 = *(const float4*)(trans + (I * 16 + col) * 48 + K * 16 + rb);
      T_[I][K].x = fexp2(t4.x * LOG2E);
      T_[I][K].y = fexp2(t4.y * LOG2E);
      T_[I][K].z = fexp2(t4.z * LOG2E);
      T_[I][K].w = fexp2(t4.w * LOG2E);
    }

  unsigned Bd[3][3][2];
#pragma unroll
  for (int K = 0; K < 3; ++K)
#pragma unroll
    for (int J = 0; J < 3; ++J) {
      const float b0 = (K == J && rb + 0 == col) ? 1.f : 0.f;
      const float b1 = (K == J && rb + 1 == col) ? 1.f : 0.f;
      const float b2 = (K == J && rb + 2 == col) ? 1.f : 0.f;
      const float b3 = (K == J && rb + 3 == col) ? 1.f : 0.f;
      Bd[K][J][0] = pk2(b0, b1);
      Bd[K][J][1] = pk2(b2, b3);
    }

  asm volatile("s_waitcnt vmcnt(0)" ::: "memory");
  __builtin_amdgcn_sched_barrier(0);

  float km = 0.f, Sacc = 0.f;
  f32x4 C[3][3];
  const f32x4 zz = {0.f, 0.f, 0.f, 0.f};

  for (int p = 0; p < SEGLEN; ++p) {
    Sacc += km;
    float ef[3];
    ef[0] = fexp2(fmaf(lds[p * 48 +  0 + col], LOG2E, -km));
    ef[1] = fexp2(fmaf(lds[p * 48 + 16 + col], LOG2E, -km));
    ef[2] = fexp2(fmaf(lds[p * 48 + 32 + col], LOG2E, -km));
    unsigned Ad[3][3][2];
#pragma unroll
    for (int I = 0; I < 3; ++I)
#pragma unroll
      for (int K = 0; K < 3; ++K) {
        Ad[I][K][0] = pk2(T_[I][K].x * ef[I], T_[I][K].y * ef[I]);
        Ad[I][K][1] = pk2(T_[I][K].z * ef[I], T_[I][K].w * ef[I]);
      }
#pragma unroll
    for (int I = 0; I < 3; ++I)
#pragma unroll
      for (int J = 0; J < 3; ++J) {
        f32x4 c = MF16(b4(Ad[I][0][0], Ad[I][0][1]), b4(Bd[0][J][0], Bd[0][J][1]), zz);
        c = MF16(b4(Ad[I][1][0], Ad[I][1][1]), b4(Bd[1][J][0], Bd[1][J][1]), c);
        c = MF16(b4(Ad[I][2][0], Ad[I][2][1]), b4(Bd[2][J][0], Bd[2][J][1]), c);
        C[I][J] = c;
      }
    const unsigned u00 = __builtin_amdgcn_readfirstlane(__float_as_uint(C[0][0][0]));
    km = (float)((int)((u00 >> 23) & 255u) - 127);
#pragma unroll
    for (int K = 0; K < 3; ++K)
#pragma unroll
      for (int J = 0; J < 3; ++J) {
        Bd[K][J][0] = pk2(C[K][J][0], C[K][J][1]);
        Bd[K][J][1] = pk2(C[K][J][2], C[K][J][3]);
      }
  }

  const unsigned gb = (unsigned)wg * GW;
#pragma unroll
  for (int I = 0; I < 3; ++I)
#pragma unroll
    for (int J = 0; J < 3; ++J)
#pragma unroll
      for (int r = 0; r < 4; ++r) {
        const float cn = dpp_xor1(C[I][J][r]);
        const unsigned pk = pk2(C[I][J][r], cn);
        if (!(col & 1))
          gws[gb + (unsigned)((I * 16 + rb + r) * 24 + ((J * 16 + col) >> 1))] = pk;
      }
  if (lane == 0) ws[SOFF + wg] = Sacc;
}

__global__ __launch_bounds__(64) void crf_tree_kernel(
    const float* __restrict__ feat, const float* __restrict__ trans,
    float* __restrict__ ws)
{
  __shared__ __align__(16) float fls[SEGLEN * 48];
  crf_tree_body(feat, trans, ws, fls, blockIdx.x, threadIdx.x);
}

// ================= phaseB: per-batch segment matvecs + tail (fence-free) =========
__device__ __attribute__((noinline)) void crf_phaseB(
    const float* __restrict__ feat, const float* __restrict__ trans,
    const int* __restrict__ seqLens, float* __restrict__ ws, int b, int lane)
{
  constexpr float LOG2E = 1.4426950408889634f;
  constexpr float LN2   = 0.6931471805599453f;
  const unsigned* gws = (const unsigned*)ws;
  const int ii = lane < 47 ? lane : 47;
  const int Lb = seqLens[b];
  const int steps = Lb - 1;                    // 0..511
  const int nfull = steps >> 4;                // full 16-step segments (<= 31)

  f16x2 E00,E01,E02,E03,E04,E05,E06,E07,E08,E09,E10,E11,
        E12,E13,E14,E15,E16,E17,E18,E19,E20,E21,E22,E23;
#define LDE(V, J) { const float e0_ = fexp2(trans[ii*48 + 2*(J)]     * LOG2E); \
                    const float e1_ = fexp2(trans[ii*48 + 2*(J) + 1] * LOG2E); \
                    V = __builtin_amdgcn_cvt_pkrtz(e0_, e1_); }
  LDE(E00,0)  LDE(E01,1)  LDE(E02,2)  LDE(E03,3)  LDE(E04,4)  LDE(E05,5)
  LDE(E06,6)  LDE(E07,7)  LDE(E08,8)  LDE(E09,9)  LDE(E10,10) LDE(E11,11)
  LDE(E12,12) LDE(E13,13) LDE(E14,14) LDE(E15,15) LDE(E16,16) LDE(E17,17)
  LDE(E18,18) LDE(E19,19) LDE(E20,20) LDE(E21,21) LDE(E22,22) LDE(E23,23)
#undef LDE
  const float tS = trans[ii * 48 + START_ID];
  const float tE = trans[END_ID * 48 + ii];
  const float* fb = feat + (size_t)b * (LL * TT);

  const float a0 = (tS + fb[ii]) * LOG2E;
  const float anch = rfirst(a0);
  float v = fexp2(a0 - anch);
  float sigma = anch;

#define RL24                                                               \
        unsigned s00,s01,s02,s03,s04,s05,s06,s07,s08,s09,s10,s11,          \
                 s12,s13,s14,s15,s16,s17,s18,s19,s20,s21,s22,s23;          \
        s00=__builtin_amdgcn_readlane(pku,0);  s01=__builtin_amdgcn_readlane(pku,2);  \
        s02=__builtin_amdgcn_readlane(pku,4);  s03=__builtin_amdgcn_readlane(pku,6);  \
        s04=__builtin_amdgcn_readlane(pku,8);  s05=__builtin_amdgcn_readlane(pku,10); \
        s06=__builtin_amdgcn_readlane(pku,12); s07=__builtin_amdgcn_readlane(pku,14); \
        s08=__builtin_amdgcn_readlane(pku,16); s09=__builtin_amdgcn_readlane(pku,18); \
        s10=__builtin_amdgcn_readlane(pku,20); s11=__builtin_amdgcn_readlane(pku,22); \
        s12=__builtin_amdgcn_readlane(pku,24); s13=__builtin_amdgcn_readlane(pku,26); \
        s14=__builtin_amdgcn_readlane(pku,28); s15=__builtin_amdgcn_readlane(pku,30); \
        s16=__builtin_amdgcn_readlane(pku,32); s17=__builtin_amdgcn_readlane(pku,34); \
        s18=__builtin_amdgcn_readlane(pku,36); s19=__builtin_amdgcn_readlane(pku,38); \
        s20=__builtin_amdgcn_readlane(pku,40); s21=__builtin_amdgcn_readlane(pku,42); \
        s22=__builtin_amdgcn_readlane(pku,44); s23=__builtin_amdgcn_readlane(pku,46);

  // ---- segment matvecs with 1-ahead register prefetch of G ----
  const unsigned* grow = gws + (size_t)(b * SEGS) * GW + ii * 24;
  u32x4 h0,h1,h2,h3,h4,h5, n0,n1,n2,n3,n4,n5;
  if (nfull > 0) {
    const u32x4* gp = (const u32x4*)grow;
    h0 = gp[0]; h1 = gp[1]; h2 = gp[2]; h3 = gp[3]; h4 = gp[4]; h5 = gp[5];
  }
  for (int s = 0; s < nfull; ++s) {
    if (s + 1 < nfull) {
      const u32x4* gp = (const u32x4*)(grow + (size_t)(s + 1) * GW);
      n0 = gp[0]; n1 = gp[1]; n2 = gp[2]; n3 = gp[3]; n4 = gp[4]; n5 = gp[5];
    }
    const float pn = dpp_xor1(v);
    const unsigned pku = pk2(v, pn);
    RL24
    float d0, d1, d2, d3;
    d0 = fdot2(bc(h0.x), bc(s00), 0.0f);
    d1 = fdot2(bc(h0.y), bc(s01), 0.0f);
    d2 = fdot2(bc(h0.z), bc(s02), 0.0f);
    d3 = fdot2(bc(h0.w), bc(s03), 0.0f);
    d0 = fdot2(bc(h1.x), bc(s04), d0);
    d1 = fdot2(bc(h1.y), bc(s05), d1);
    d2 = fdot2(bc(h1.z), bc(s06), d2);
    d3 = fdot2(bc(h1.w), bc(s07), d3);
    d0 = fdot2(bc(h2.x), bc(s08), d0);
    d1 = fdot2(bc(h2.y), bc(s09), d1);
    d2 = fdot2(bc(h2.z), bc(s10), d2);
    d3 = fdot2(bc(h2.w), bc(s11), d3);
    d0 = fdot2(bc(h3.x), bc(s12), d0);
    d1 = fdot2(bc(h3.y), bc(s13), d1);
    d2 = fdot2(bc(h3.z), bc(s14), d2);
    d3 = fdot2(bc(h3.w), bc(s15), d3);
    d0 = fdot2(bc(h4.x), bc(s16), d0);
    d1 = fdot2(bc(h4.y), bc(s17), d1);
    d2 = fdot2(bc(h4.z), bc(s18), d2);
    d3 = fdot2(bc(h4.w), bc(s19), d3);
    d0 = fdot2(bc(h5.x), bc(s20), d0);
    d1 = fdot2(bc(h5.y), bc(s21), d1);
    d2 = fdot2(bc(h5.z), bc(s22), d2);
    d3 = fdot2(bc(h5.w), bc(s23), d3);
    const float dot = (d0 + d1) + (d2 + d3);
    const unsigned ub = __builtin_amdgcn_readfirstlane(__float_as_uint(dot));
    const int e = (int)((ub >> 23) & 255u) - 127;
    v = dot * __uint_as_float((unsigned)(127 - e) << 23);
    sigma += (float)e + ws[SOFF + b * SEGS + s];
    h0 = n0; h1 = n1; h2 = n2; h3 = n3; h4 = n4; h5 = n5;
  }

  // ---- tail: t = 16*nfull+1 .. steps (<= 15 scalar steps) ----
  int t = nfull * 16 + 1;
  if (t <= steps) {
    float f_cur = fb[(size_t)t * 48 + ii];
    for (; t <= steps; ++t) {
      const int tn = (t + 1 <= steps) ? t + 1 : t;
      const float f_nxt = fb[(size_t)tn * 48 + ii];
      const float pn = dpp_xor1(v);
      const unsigned pku = pk2(v, pn);
      RL24
      float d0, d1, d2, d3;
      d0 = fdot2(E00, bc(s00), 0.0f);
      d1 = fdot2(E01, bc(s01), 0.0f);
      d2 = fdot2(E02, bc(s02), 0.0f);
      d3 = fdot2(E03, bc(s03), 0.0f);
      d0 = fdot2(E04, bc(s04), d0);
      d1 = fdot2(E05, bc(s05), d1);
      d2 = fdot2(E06, bc(s06), d2);
      d3 = fdot2(E07, bc(s07), d3);
      d0 = fdot2(E08, bc(s08), d0);
      d1 = fdot2(E09, bc(s09), d1);
      d2 = fdot2(E10, bc(s10), d2);
      d3 = fdot2(E11, bc(s11), d3);
      d0 = fdot2(E12, bc(s12), d0);
      d1 = fdot2(E13, bc(s13), d1);
      d2 = fdot2(E14, bc(s14), d2);
      d3 = fdot2(E15, bc(s15), d3);
      d0 = fdot2(E16, bc(s16), d0);
      d1 = fdot2(E17, bc(s17), d1);
      d2 = fdot2(E18, bc(s18), d2);
      d3 = fdot2(E19, bc(s19), d3);
      d0 = fdot2(E20, bc(s20), d0);
      d1 = fdot2(E21, bc(s21), d1);
      d2 = fdot2(E22, bc(s22), d2);
      d3 = fdot2(E23, bc(s23), d3);
      const float dot = (d0 + d1) + (d2 + d3);
      const float w = dot * fexp2(f_cur * LOG2E);
      const unsigned ub = __builtin_amdgcn_readfirstlane(__float_as_uint(w));
      const int e = (int)((ub >> 23) & 255u) - 127;
      v = w * __uint_as_float((unsigned)(127 - e) << 23);
      sigma += (float)e;
      f_cur = f_nxt;
    }
  }
#undef RL24

  float contrib = (lane < 48) ? v * fexp2(tE * LOG2E) : 0.0f;
#pragma unroll
  for (int off = 32; off; off >>= 1) contrib += __shfl_xor(contrib, off, 64);
  if (lane == 0) ws[ZOFF + b] = (flog2(contrib) + sigma) * LN2;
}

// ================= writer body: non-temporal float4 stores =================
__device__ __forceinline__ void scores_writer_rng(
    const float* __restrict__ feat, float* __restrict__ out,
    float* lds, unsigned k, unsigned kstride, unsigned kend)
{
  for (; k < kend; k += kstride) {
    const unsigned idx = 3u + 4u * k;
    const unsigned r0 = idx / 48u;
    const unsigned j0 = idx - r0 * 48u;
    const unsigned i0 = r0 % 48u;
    const unsigned rn = (r0 + 1u < (unsigned)BLT) ? r0 + 1u : (unsigned)(BLT - 1);
    const float fa = feat[r0];
    const float fn = feat[rn];
    const unsigned i1 = (i0 + 1u < 48u) ? i0 + 1u : 0u;
    float v[4];
#pragma unroll
    for (int e = 0; e < 4; ++e) {
      const unsigned j = j0 + (unsigned)e;
      const bool wr = j >= 48u;
      const unsigned jj = wr ? j - 48u : j;
      v[e] = (wr ? fn : fa) + lds[(wr ? i1 : i0) * 48u + jj];
    }
    f32x4 o; o.x = v[0]; o.y = v[1]; o.z = v[2]; o.w = v[3];
    __builtin_nontemporal_store(o, (f32x4*)(out + 4u + 4u * (size_t)k));
  }
}

// ================= fused: phaseB blocks + writer blocks (R3 structure) ==========
__global__ __launch_bounds__(256) void crf_fusedB_kernel(
    const float* __restrict__ feat, const float* __restrict__ trans,
    const int* __restrict__ seqLens, float* __restrict__ out,
    float* __restrict__ ws)
{
  __shared__ __align__(16) float lds[2304];
  const int blk = blockIdx.x;
  if (blk < BB) {
    if (threadIdx.x >= 64) return;
    crf_phaseB(feat, trans, seqLens, ws, blk, threadIdx.x);
    return;
  }
  for (int s = threadIdx.x; s < 2304; s += 256) lds[s] = trans[s];
  __syncthreads();
  scores_writer_rng(feat, out, lds,
                    (unsigned)(blk - BB) * 256u + threadIdx.x,
                    (gridDim.x - BB) * 256u, NGRP);
}

__global__ void crf_finalize_kernel(const float* __restrict__ feat,
                                    const float* __restrict__ trans,
                                    const float* __restrict__ zws,
                                    float* __restrict__ out)
{
  const int t = threadIdx.x;
  float v = (t < 32) ? zws[t] : 0.0f;
#pragma unroll
  for (int off = 32; off; off >>= 1) v += __shfl_xor(v, off, 64);
  if (t == 0) out[0] = v;
  else if (t <= 3) out[t] = feat[0] + trans[t - 1];
  else if (t == 4) out[NSC] = feat[BLT - 1] + trans[2303];
}

// ================= ws-too-small fallback: verified 88us scalar recursion ========
__device__ __attribute__((noinline)) void crf_recursion_body(
    const float* __restrict__ feat, const float* __restrict__ trans,
    const int* __restrict__ seqLens, float* __restrict__ ws,
    float* lds, int blk, int lane)
{
  constexpr float LOG2E = 1.4426950408889634f;
  const int ii = lane < 47 ? lane : 47;
  const char* gbase = (const char*)(feat + (size_t)blk * (LL * TT));
  const int Lb = seqLens[blk];

#pragma unroll
  for (int w = 0; w < 6; ++w)
    GLD16(gbase + w * 1024 + lane * 16, (char*)&lds[0] + w * 1024);

  f16x2 E00,E01,E02,E03,E04,E05,E06,E07,E08,E09,E10,E11,
        E12,E13,E14,E15,E16,E17,E18,E19,E20,E21,E22,E23;
#define LDE(V, J) { const float e0_ = fexp2(trans[ii*48 + 2*(J)]     * LOG2E); \
                    const float e1_ = fexp2(trans[ii*48 + 2*(J) + 1] * LOG2E); \
                    V = __builtin_amdgcn_cvt_pkrtz(e0_, e1_); }
  LDE(E00,0)  LDE(E01,1)  LDE(E02,2)  LDE(E03,3)  LDE(E04,4)  LDE(E05,5)
  LDE(E06,6)  LDE(E07,7)  LDE(E08,8)  LDE(E09,9)  LDE(E10,10) LDE(E11,11)
  LDE(E12,12) LDE(E13,13) LDE(E14,14) LDE(E15,15) LDE(E16,16) LDE(E17,17)
  LDE(E18,18) LDE(E19,19) LDE(E20,20) LDE(E21,21) LDE(E22,22) LDE(E23,23)
#undef LDE
  const float tS = trans[ii * 48 + START_ID];
  const float tE = trans[END_ID * 48 + ii];

  asm volatile("s_waitcnt vmcnt(0)" ::: "memory");
  __builtin_amdgcn_sched_barrier(0);

  const float f00 = lds[ii];
  float a2 = (tS + f00) * LOG2E;
  float M2 = rfirst(a2) + 5.0f;

  const int nch = (Lb + 31) >> 5;
  for (int c = 0; c < nch; ++c) {
    const bool pre = (c + 1 < nch);
    if (pre) {
      const char* g = gbase + (size_t)(c + 1) * 6144;
      char* l = (char*)&lds[((c + 1) & 1) * 1536];
#pragma unroll
      for (int w = 0; w < 6; ++w) GLD16(g + w * 1024 + lane * 16, l + w * 1024);
    }
    const int tend = ((c + 1) * 32 < Lb) ? (c + 1) * 32 : Lb;
    const int t0 = (c == 0 ? 1 : c * 32);
    const int base = (c & 1) * 1536 + ii;
    if (t0 < tend) {
      float f_cur = lds[base + (t0 - c * 32) * 48];
      for (int t = t0; t < tend; ++t) {
        const int lnxt = ((t + 1 < tend) ? t + 1 : t) - c * 32;
        const float f_nxt = lds[base + lnxt * 48];
        const float p  = fexp2(a2 - M2);
        const float pn = dpp_xor1(p);
        const unsigned pku = pk2(p, pn);
        unsigned s00,s01,s02,s03,s04,s05,s06,s07,s08,s09,s10,s11,
                 s12,s13,s14,s15,s16,s17,s18,s19,s20,s21,s22,s23;
#define RL(K) __builtin_amdgcn_readlane(pku, (K))
        s00=RL(0);  s01=RL(2);  s02=RL(4);  s03=RL(6);
        s04=RL(8);  s05=RL(10); s06=RL(12); s07=RL(14);
        s08=RL(16); s09=RL(18); s10=RL(20); s11=RL(22);
        s12=RL(24); s13=RL(26); s14=RL(28); s15=RL(30);
        s16=RL(32); s17=RL(34); s18=RL(36); s19=RL(38);
        s20=RL(40); s21=RL(42); s22=RL(44); s23=RL(46);
#undef RL
        float d0, d1, d2, d3;
        d0 = fdot2(E00, bc(s00), 0.0f);
        d1 = fdot2(E01, bc(s01), 0.0f);
        d2 = fdot2(E02, bc(s02), 0.0f);
        d3 = fdot2(E03, bc(s03), 0.0f);
        d0 = fdot2(E04, bc(s04), d0);
        d1 = fdot2(E05, bc(s05), d1);
        d2 = fdot2(E06, bc(s06), d2);
        d3 = fdot2(E07, bc(s07), d3);
        d0 = fdot2(E08, bc(s08), d0);
        d1 = fdot2(E09, bc(s09), d1);
        d2 = fdot2(E10, bc(s10), d2);
        d3 = fdot2(E11, bc(s11), d3);
        d0 = fdot2(E12, bc(s12), d0);
        d1 = fdot2(E13, bc(s13), d1);
        d2 = fdot2(E14, bc(s14), d2);
        d3 = fdot2(E15, bc(s15), d3);
        d0 = fdot2(E16, bc(s16), d0);
        d1 = fdot2(E17, bc(s17), d1);
        d2 = fdot2(E18, bc(s18), d2);
        d3 = fdot2(E19, bc(s19), d3);
        d0 = fdot2(E20, bc(s20), d0);
        d1 = fdot2(E21, bc(s21), d1);
        d2 = fdot2(E22, bc(s22), d2);
        d3 = fdot2(E23, bc(s23), d3);
        const float dot = (d0 + d1) + (d2 + d3);
        a2 = fmaf(f_cur, LOG2E, M2 + flog2(dot));
        M2 = rfirst(a2) + 5.0f;
        f_cur = f_nxt;
      }
    }
    asm volatile("s_waitcnt vmcnt(0)" ::: "memory");
    __builtin_amdgcn_sched_barrier(0);
  }

  float last2 = (lane < 48) ? (a2 + tE * LOG2E) : -3.0e38f;
  float m2 = last2;
#pragma unroll
  for (int off = 32; off; off >>= 1) m2 = fmaxf(m2, __shfl_xor(m2, off, 64));
  float e = (lane < 48) ? fexp2(last2 - m2) : 0.0f;
#pragma unroll
  for (int off = 32; off; off >>= 1) e += __shfl_xor(e, off, 64);
  if (lane == 0) ws[blk] = (m2 + flog2(e)) * 0.6931471805599453f;
}

__global__ __launch_bounds__(256) void crf_fused2_kernel(
    const float* __restrict__ feat, const float* __restrict__ trans,
    const int* __restrict__ seqLens, float* __restrict__ out,
    float* __restrict__ ws)
{
  __shared__ __align__(16) float lds[3072];
  const int blk = blockIdx.x;
  if (blk < BB) {
    if (threadIdx.x >= 64) return;
    crf_recursion_body(feat, trans, seqLens, ws, lds, blk, threadIdx.x);
    return;
  }
  for (int s = threadIdx.x; s < 2304; s += 256) lds[s] = trans[s];
  __syncthreads();
  scores_writer_rng(feat, out, lds,
                    (unsigned)(blk - BB) * 256u + threadIdx.x,
                    (gridDim.x - BB) * 256u, NGRP);
}

// ================= host =================
extern "C" void kernel_launch(void* const* d_in, const int* in_sizes, int n_in,
                              void* d_out, int out_size, void* d_ws, size_t ws_size,
                              hipStream_t stream) {
  const float* feat    = (const float*)d_in[0];
  const float* trans   = (const float*)d_in[1];
  const int*   seqLens = (const int*)d_in[2];
  float* out = (float*)d_out;
  float* ws  = (float*)d_ws;

  if (ws_size >= WS_NEED) {
    hipLaunchKernelGGL(crf_tree_kernel, dim3(NSEG), dim3(64), 0, stream,
                       feat, trans, ws);
    hipLaunchKernelGGL(crf_fusedB_kernel, dim3(2048), dim3(256), 0, stream,
                       feat, trans, seqLens, out, ws);
    hipLaunchKernelGGL(crf_finalize_kernel, dim3(1), dim3(64), 0, stream,
                       feat, trans, ws + ZOFF, out);
  } else {
    hipLaunchKernelGGL(crf_fused2_kernel, dim3(2048), dim3(256), 0, stream,
                       feat, trans, seqLens, out, ws);
    hipLaunchKernelGGL(crf_finalize_kernel, dim3(1), dim3(64), 0, stream,
                       feat, trans, ws, out);
  }
}